// Round 1
// baseline (191.700 us; speedup 1.0000x reference)
//
#include <hip/hip_runtime.h>
#include <hip/hip_bf16.h>

#define UNITS   64
#define NPROD1  2080
#define NPROD2  45760
#define KTOT    (UNITS + NPROD1 + NPROD2)   // 47904
#define KSTEPS  (KTOT / 32)                 // 1497 (exact)
#define SPLITK  16
#define STEPS_PER ((KSTEPS + SPLITK - 1) / SPLITK)  // 94
#define NB      4096
#define ND      66
#define FSTRIDE 65   // 64 f values + sentinel 1.0

typedef __attribute__((ext_vector_type(8))) __bf16 bf16x8;
typedef __attribute__((ext_vector_type(4))) float  f32x4;

// Static device scratch (avoids depending on ws_size). Rewritten every launch.
__device__ __attribute__((aligned(16))) unsigned int g_idx[KTOT];
__device__ __attribute__((aligned(16))) float        g_f[NB * FSTRIDE];
__device__ __attribute__((aligned(16))) __bf16       g_woT[UNITS * KTOT];

// --- build packed (a,b,c) monomial table; sentinel index 64 -> f==1.0 ---
__global__ void k_build_idx() {
    int k = blockIdx.x * 256 + threadIdx.x;
    if (k >= KTOT) return;
    int a, b, c;
    if (k < UNITS) {                 // singles: (a, 1, 1)
        a = k; b = 64; c = 64;
    } else if (k < UNITS + NPROD1) { // pairs (a<=b): (a, b, 1)
        int p = k - UNITS;
        a = 0;
        while (p >= UNITS - a) { p -= UNITS - a; ++a; }
        b = a + p; c = 64;
    } else {                         // triples a<=b<=c, lex order
        int t = k - UNITS - NPROD1;
        a = 0;
        for (;;) {
            int cnt = (UNITS - a) * (UNITS - a + 1) / 2;
            if (t < cnt) break;
            t -= cnt; ++a;
        }
        b = a;
        while (t >= UNITS - b) { t -= UNITS - b; ++b; }
        c = b + t;
    }
    g_idx[k] = (unsigned)a | ((unsigned)b << 8) | ((unsigned)c << 16);
}

// --- Fourier features f[r][0..63], sentinel 1.0 at col 64 ---
__global__ void k_f(const float* __restrict__ inp, const float* __restrict__ fw1,
                    const float* __restrict__ fw2, const float* __restrict__ fb1) {
    int i = blockIdx.x * 256 + threadIdx.x;
    if (i >= NB * FSTRIDE) return;
    int r = i / FSTRIDE, c = i % FSTRIDE;
    float v;
    if (c < UNITS) v = cosf(inp[r * ND + c] * fw1[c] + fb1[c]) * fw2[c];
    else           v = 1.0f;
    g_f[i] = v;
}

// --- transpose + convert wo[47904][64] fp32 -> woT[64][47904] bf16 ---
__global__ void k_wot(const float* __restrict__ wo) {
    __shared__ float tile[64 * 64];
    int k0 = blockIdx.x * 64;
    for (int e = threadIdx.x; e < 64 * 64; e += 256) {
        int kl = e >> 6, n = e & 63;
        int k = k0 + kl;
        tile[e] = (k < KTOT) ? wo[k * UNITS + n] : 0.0f;
    }
    __syncthreads();
    for (int e = threadIdx.x; e < 64 * 64; e += 256) {
        int n = e >> 6, kl = e & 63;
        int k = k0 + kl;
        if (k < KTOT) g_woT[n * KTOT + k] = (__bf16)tile[kl * 64 + n];
    }
}

// --- out = inputs (gives the +x residual AND the 2 passthrough pad cols) ---
__global__ void k_init(const float* __restrict__ inp, float* __restrict__ out) {
    int i = blockIdx.x * 256 + threadIdx.x;
    if (i < NB * ND) out[i] = inp[i];
}

// --- main GEMM: on-the-fly comb tile (A) x woT (B), split-K, atomic epilogue ---
__global__ __launch_bounds__(256) void k_gemm(float* __restrict__ out) {
    __shared__ float fl[64 * FSTRIDE];
    const int mb = blockIdx.x;   // 64 M-blocks of 64 rows
    const int ks = blockIdx.y;   // SPLITK K-chunks
    const int tid = threadIdx.x;

    for (int e = tid; e < 64 * FSTRIDE; e += 256)
        fl[e] = g_f[mb * 64 * FSTRIDE + e];
    __syncthreads();

    const int wave = tid >> 6, lane = tid & 63;
    const int rl = lane & 15, g = lane >> 4;
    const float* fr = fl + (wave * 16 + rl) * FSTRIDE;  // this lane's f row
    const __bf16* wb = g_woT + rl * KTOT;

    f32x4 acc0{0.f,0.f,0.f,0.f}, acc1{0.f,0.f,0.f,0.f};
    f32x4 acc2{0.f,0.f,0.f,0.f}, acc3{0.f,0.f,0.f,0.f};

    const int s0 = ks * STEPS_PER;
    const int s1 = (s0 + STEPS_PER < KSTEPS) ? s0 + STEPS_PER : KSTEPS;

    for (int s = s0; s < s1; ++s) {
        const int k0 = s * 32 + g * 8;
        uint4 p0 = *reinterpret_cast<const uint4*>(g_idx + k0);
        uint4 p1 = *reinterpret_cast<const uint4*>(g_idx + k0 + 4);
        unsigned pk[8] = {p0.x, p0.y, p0.z, p0.w, p1.x, p1.y, p1.z, p1.w};

        float v[8];
#pragma unroll
        for (int j = 0; j < 8; ++j) {
            unsigned q = pk[j];
            v[j] = fr[q & 127] * fr[(q >> 8) & 127] * fr[(q >> 16) & 127];
        }
        bf16x8 af;
#pragma unroll
        for (int j = 0; j < 8; ++j) af[j] = (__bf16)v[j];

        const bf16x8 b0 = *reinterpret_cast<const bf16x8*>(wb + 0 * 16 * KTOT + k0);
        const bf16x8 b1 = *reinterpret_cast<const bf16x8*>(wb + 1 * 16 * KTOT + k0);
        const bf16x8 b2 = *reinterpret_cast<const bf16x8*>(wb + 2 * 16 * KTOT + k0);
        const bf16x8 b3 = *reinterpret_cast<const bf16x8*>(wb + 3 * 16 * KTOT + k0);

        acc0 = __builtin_amdgcn_mfma_f32_16x16x32_bf16(af, b0, acc0, 0, 0, 0);
        acc1 = __builtin_amdgcn_mfma_f32_16x16x32_bf16(af, b1, acc1, 0, 0, 0);
        acc2 = __builtin_amdgcn_mfma_f32_16x16x32_bf16(af, b2, acc2, 0, 0, 0);
        acc3 = __builtin_amdgcn_mfma_f32_16x16x32_bf16(af, b3, acc3, 0, 0, 0);
    }

    // D layout (m89-verified): col = lane&15, row = (lane>>4)*4 + reg
    const int orow = mb * 64 + wave * 16 + g * 4;
#pragma unroll
    for (int i2 = 0; i2 < 4; ++i2) {
        atomicAdd(&out[(orow + i2) * ND +  0 + rl], acc0[i2]);
        atomicAdd(&out[(orow + i2) * ND + 16 + rl], acc1[i2]);
        atomicAdd(&out[(orow + i2) * ND + 32 + rl], acc2[i2]);
        atomicAdd(&out[(orow + i2) * ND + 48 + rl], acc3[i2]);
    }
}

extern "C" void kernel_launch(void* const* d_in, const int* in_sizes, int n_in,
                              void* d_out, int out_size, void* d_ws, size_t ws_size,
                              hipStream_t stream) {
    const float* inp = (const float*)d_in[0];
    const float* fw1 = (const float*)d_in[1];
    const float* fw2 = (const float*)d_in[2];
    const float* fb1 = (const float*)d_in[3];
    const float* wo  = (const float*)d_in[4];
    float* out = (float*)d_out;

    k_build_idx<<<(KTOT + 255) / 256, 256, 0, stream>>>();
    k_f<<<(NB * FSTRIDE + 255) / 256, 256, 0, stream>>>(inp, fw1, fw2, fb1);
    k_wot<<<(KTOT + 63) / 64, 256, 0, stream>>>(wo);
    k_init<<<(NB * ND + 255) / 256, 256, 0, stream>>>(inp, out);
    k_gemm<<<dim3(64, SPLITK), 256, 0, stream>>>(out);
}

// Round 2
// 114.644 us; speedup vs baseline: 1.6721x; 1.6721x over previous
//
#include <hip/hip_runtime.h>
#include <hip/hip_bf16.h>

#define UNITS   64
#define NPROD1  2080
#define NPROD2  45760
#define KTOT    47904
#define KPAD    55744            // 64 + 2304 + 53376 (aligned-octet padded runs)
#define NGRP    (KPAD/8)         // 6968 groups
#define NSTEP   (KPAD/32)        // 1742 MFMA K-steps
#define SPLITK  16
#define STEPS_PER ((NSTEP + SPLITK - 1)/SPLITK)  // 109
#define NB      4096
#define ND      66
#define FS      76               // f row stride in floats (76 mod 32 = 12 -> 2-way banks)
#define PAIR_BASE 64
#define TRIP_BASE 2368

typedef __attribute__((ext_vector_type(8))) __bf16 bf16x8;
typedef __attribute__((ext_vector_type(4))) float  f32x4;

// Static device scratch, rewritten every launch (deterministic).
__device__ __attribute__((aligned(16))) float    g_f[NB * FS];
__device__ __attribute__((aligned(16))) __bf16   g_woTi[(size_t)64 * KPAD]; // MFMA-interleaved
__device__ __attribute__((aligned(16))) unsigned g_perm[KTOT];
__device__ __attribute__((aligned(16))) unsigned g_grp[NGRP];
__device__ int g_pb[64];   // prefix of run lengths (pairs region); also r2-prefix
__device__ int g_sp[64];   // prefix of S(a) for triples region

// run length for last-index variable v: R(v) = 64 - 8*(v>>3)
__global__ void k_prefix() {
    __shared__ int S[64];
    int a = threadIdx.x;   // 64 threads
    int s = 0;
    for (int b = a; b < 64; ++b) s += 64 - 8 * (b >> 3);
    S[a] = s;
    int pb = 0;
    for (int x = 0; x < a; ++x) pb += 64 - 8 * (x >> 3);
    g_pb[a] = pb;          // serves as both PairBase(a) and R2-prefix(a)
    __syncthreads();
    int sp = 0;
    for (int x = 0; x < a; ++x) sp += S[x];
    g_sp[a] = sp;
}

// map original k -> permuted k'
__global__ void k_perm() {
    int k = blockIdx.x * 256 + threadIdx.x;
    if (k >= KTOT) return;
    unsigned dest;
    if (k < 64) {
        dest = (unsigned)k;
    } else if (k < 64 + NPROD1) {
        int p = k - 64;
        int a = 0;
        while (p >= 64 - a) { p -= 64 - a; ++a; }
        int b = a + p;
        dest = PAIR_BASE + g_pb[a] + (b - 8 * (a >> 3));
    } else {
        int t = k - 64 - NPROD1;
        int a = 0;
        for (;;) { int cnt = (64 - a) * (65 - a) / 2; if (t < cnt) break; t -= cnt; ++a; }
        int b = a;
        while (t >= 64 - b) { t -= 64 - b; ++b; }
        int c = b + t;
        dest = TRIP_BASE + (g_sp[a] + g_pb[b] - g_pb[a]) + (c - 8 * (b >> 3));
    }
    g_perm[k] = dest;
}

// group descriptors: pack(s0, s1, cbase); value[j] = f[s0]*f[s1]*f[cbase+j]
__global__ void k_grp() {
    int r = blockIdx.x * 256 + threadIdx.x;
    if (r >= 1 + 64 + NPROD1) return;
    if (r == 0) {                       // singles: f[c] * 1 * 1
        for (int t = 0; t < 8; ++t)
            g_grp[t] = 64u | (64u << 8) | ((unsigned)(8 * t) << 16);
    } else if (r <= 64) {               // pairs: f[a] * 1 * f[b]
        int a = r - 1;
        int gb = 8 + g_pb[a] / 8;
        int o = a >> 3, ng = 8 - o, cb = 8 * o;
        for (int t = 0; t < ng; ++t)
            g_grp[gb + t] = (unsigned)a | (64u << 8) | ((unsigned)(cb + 8 * t) << 16);
    } else {                            // triples: f[a] * f[b] * f[c]
        int p = r - 65;
        int a = 0;
        while (p >= 64 - a) { p -= 64 - a; ++a; }
        int b = a + p;
        int gb = TRIP_BASE / 8 + (g_sp[a] + g_pb[b] - g_pb[a]) / 8;
        int o = b >> 3, ng = 8 - o, cb = 8 * o;
        for (int t = 0; t < ng; ++t)
            g_grp[gb + t] = (unsigned)a | ((unsigned)b << 8) | ((unsigned)(cb + 8 * t) << 16);
    }
}

__global__ void k_zero() {              // zero woTi (pads must be 0)
    size_t i = (size_t)blockIdx.x * 256 + threadIdx.x;
    ((uint4*)g_woTi)[i] = uint4{0, 0, 0, 0};
}

// scatter wo[k][n] fp32 -> interleaved bf16 at permuted k'
// layout: step s block = 2048 bf16; [q(4)][g(4)][rl(16)][j(8)]
__global__ void k_wot(const float* __restrict__ wo) {
    int gid = blockIdx.x * 256 + threadIdx.x;   // 47904*64 exact grid
    int k = gid >> 6, n = gid & 63;
    unsigned kp = g_perm[k];
    unsigned s = kp >> 5, kin = kp & 31, g = kin >> 3, j = kin & 7;
    unsigned q = (unsigned)n >> 4, rl = (unsigned)n & 15;
    g_woTi[(size_t)((s * 4 + q) * 64 + g * 16 + rl) * 8 + j] = (__bf16)wo[gid];
}

// Fourier features, sentinel 1.0 at col 64, zeros in pad cols
__global__ void k_f(const float* __restrict__ inp, const float* __restrict__ fw1,
                    const float* __restrict__ fw2, const float* __restrict__ fb1) {
    int i = blockIdx.x * 256 + threadIdx.x;
    if (i >= NB * FS) return;
    int r = i / FS, c = i % FS;
    float v;
    if (c < 64)      v = cosf(inp[r * ND + c] * fw1[c] + fb1[c]) * fw2[c];
    else if (c == 64) v = 1.0f;
    else             v = 0.0f;
    g_f[i] = v;
}

__global__ void k_init(const float* __restrict__ inp, float* __restrict__ out) {
    int i = blockIdx.x * 256 + threadIdx.x;
    if (i < NB * ND) out[i] = inp[i];
}

__global__ __launch_bounds__(256) void k_gemm(float* __restrict__ out) {
    __shared__ __attribute__((aligned(16))) float fl[64 * FS];
    __shared__ unsigned lgrp[STEPS_PER * 4];
    const int mb = blockIdx.x, ks = blockIdx.y, tid = threadIdx.x;
    const int s0 = ks * STEPS_PER;
    const int s1 = (s0 + STEPS_PER < NSTEP) ? s0 + STEPS_PER : NSTEP;
    const int ns = s1 - s0;

    for (int e = tid; e < 64 * FS / 4; e += 256)
        ((f32x4*)fl)[e] = ((const f32x4*)(g_f + (size_t)mb * 64 * FS))[e];
    for (int e = tid; e < ns * 4; e += 256) lgrp[e] = g_grp[s0 * 4 + e];
    __syncthreads();

    const int wave = tid >> 6, lane = tid & 63, rl = lane & 15, g = lane >> 4;
    const float* fr = fl + (wave * 16 + rl) * FS;

    f32x4 acc0{0.f,0.f,0.f,0.f}, acc1{0.f,0.f,0.f,0.f};
    f32x4 acc2{0.f,0.f,0.f,0.f}, acc3{0.f,0.f,0.f,0.f};

    for (int s = s0; s < s1; ++s) {
        const unsigned pk = lgrp[(s - s0) * 4 + g];
        const float pab = fr[pk & 127] * fr[(pk >> 8) & 127];
        const int cb = (pk >> 16) & 127;
        const f32x4 c0 = *(const f32x4*)(fr + cb);
        const f32x4 c1 = *(const f32x4*)(fr + cb + 4);
        bf16x8 af;
        af[0] = (__bf16)(pab * c0.x); af[1] = (__bf16)(pab * c0.y);
        af[2] = (__bf16)(pab * c0.z); af[3] = (__bf16)(pab * c0.w);
        af[4] = (__bf16)(pab * c1.x); af[5] = (__bf16)(pab * c1.y);
        af[6] = (__bf16)(pab * c1.z); af[7] = (__bf16)(pab * c1.w);

        const bf16x8* bp = (const bf16x8*)(g_woTi + (size_t)s * 2048) + g * 16 + rl;
        const bf16x8 b0 = bp[0], b1 = bp[64], b2 = bp[128], b3 = bp[192];

        acc0 = __builtin_amdgcn_mfma_f32_16x16x32_bf16(af, b0, acc0, 0, 0, 0);
        acc1 = __builtin_amdgcn_mfma_f32_16x16x32_bf16(af, b1, acc1, 0, 0, 0);
        acc2 = __builtin_amdgcn_mfma_f32_16x16x32_bf16(af, b2, acc2, 0, 0, 0);
        acc3 = __builtin_amdgcn_mfma_f32_16x16x32_bf16(af, b3, acc3, 0, 0, 0);
    }

    // D layout: col = lane&15, row = (lane>>4)*4 + reg
    const int orow = mb * 64 + wave * 16 + g * 4;
#pragma unroll
    for (int i2 = 0; i2 < 4; ++i2) {
        atomicAdd(&out[(orow + i2) * ND +  0 + rl], acc0[i2]);
        atomicAdd(&out[(orow + i2) * ND + 16 + rl], acc1[i2]);
        atomicAdd(&out[(orow + i2) * ND + 32 + rl], acc2[i2]);
        atomicAdd(&out[(orow + i2) * ND + 48 + rl], acc3[i2]);
    }
}

extern "C" void kernel_launch(void* const* d_in, const int* in_sizes, int n_in,
                              void* d_out, int out_size, void* d_ws, size_t ws_size,
                              hipStream_t stream) {
    const float* inp = (const float*)d_in[0];
    const float* fw1 = (const float*)d_in[1];
    const float* fw2 = (const float*)d_in[2];
    const float* fb1 = (const float*)d_in[3];
    const float* wo  = (const float*)d_in[4];
    float* out = (float*)d_out;

    k_prefix<<<1, 64, 0, stream>>>();
    k_perm<<<(KTOT + 255) / 256, 256, 0, stream>>>();
    k_grp<<<(1 + 64 + NPROD1 + 255) / 256, 256, 0, stream>>>();
    k_zero<<<NSTEP, 256, 0, stream>>>();                       // 1742*256*16B = whole woTi
    k_wot<<<(KTOT * 64) / 256, 256, 0, stream>>>(wo);
    k_f<<<(NB * FS + 255) / 256, 256, 0, stream>>>(inp, fw1, fw2, fb1);
    k_init<<<(NB * ND + 255) / 256, 256, 0, stream>>>(inp, out);
    k_gemm<<<dim3(64, SPLITK), 256, 0, stream>>>(out);
}

// Round 4
// 64.473 us; speedup vs baseline: 2.9733x; 1.7782x over previous
//
#include <hip/hip_runtime.h>
#include <hip/hip_bf16.h>

#define NB      4096
#define ND      66
#define NSTEP   1748                 // padded K / 32
#define NOCT    (NSTEP*4)            // 6992 octets
#define KS      32                   // split-K chunks
#define CH      55                   // steps per chunk (32*55 >= 1748)
#define MB      16                   // M blocks of 256 rows
#define FS      72                   // f row stride (halfs)

typedef __attribute__((ext_vector_type(8))) _Float16 f16x8;
typedef __attribute__((ext_vector_type(4))) float    f32x4;

// Static device scratch, fully rewritten every launch (deterministic).
__device__ __attribute__((aligned(16))) _Float16 g_f[NB * FS];
__device__ __attribute__((aligned(16))) _Float16 g_woTi[(size_t)(NSTEP + 1) * 2048];
__device__ __attribute__((aligned(16))) unsigned g_grp[NOCT];
__device__ __attribute__((aligned(16))) float    g_part[(size_t)KS * NB * 64];

// bucket boundaries in octets (sizes 48,156,328,564,864,1228,1656,2148)
__constant__ int c_bb[9] = {0, 48, 204, 532, 1096, 1960, 3188, 4844, 6992};

// descriptor per octet: s0 | s1<<8 | cb<<16 ; value[j] = f[s0]*f[s1]*f[cb+j]
// s0=64 or s1=64 -> sentinel f==1 ; s0=65 -> pad (f==0)
__global__ void k_desc() {
    int o = blockIdx.x * 256 + threadIdx.x;
    if (o >= NOCT) return;
    int t = 0;
    while (o >= c_bb[t + 1]) ++t;
    int li = o - c_bb[t];
    int P = 8 * t + 8;
    int T = P * (P + 1) / 2;
    int s0, s1;
    if (li == 0)            { s0 = 64; s1 = 64; }
    else if (li <= P)       { s0 = li - 1; s1 = 64; }
    else if (li <= P + T) {
        int r = li - P - 1, a = 0;
        while (r >= P - a) { r -= P - a; ++a; }
        s0 = a; s1 = a + r;
    } else                  { s0 = 65; s1 = 65; }
    g_grp[o] = (unsigned)s0 | ((unsigned)s1 << 8) | ((unsigned)(8 * t) << 16);
}

// Fourier features fp16: cols 0..63 = cos(x*w1+b1)*w2, col 64 = 1.0, 65.. = 0
__global__ void k_f(const float* __restrict__ inp, const float* __restrict__ fw1,
                    const float* __restrict__ fw2, const float* __restrict__ fb1) {
    int i = blockIdx.x * 256 + threadIdx.x;
    if (i >= NB * FS) return;
    int r = i / FS, c = i - r * FS;
    float v;
    if (c < 64)       v = cosf(inp[r * ND + c] * fw1[c] + fb1[c]) * fw2[c];
    else if (c == 64) v = 1.0f;
    else              v = 0.0f;
    g_f[i] = (_Float16)v;
}

// Build interleaved fp16 B: element e = [s(11b)][q(2)][g(2)][rl(4)][j(3)]
__global__ void k_wot(const float* __restrict__ wo) {
    int e = blockIdx.x * 256 + threadIdx.x;          // NSTEP*2048 exact
    int s = e >> 11, r = e & 2047;
    int q = r >> 9, gg = (r >> 7) & 3, rl = (r >> 3) & 15, j = r & 7;
    unsigned d = g_grp[s * 4 + gg];
    int s0 = d & 255, s1 = (d >> 8) & 255, cb = d >> 16;
    int n = q * 16 + rl;
    float val = 0.0f;
    if (s0 < 64) {
        if (s1 == 64) {                              // pair (a=s0, b=cb+j)
            int a = s0, b = cb + j;
            if (b >= a) val = wo[(64 + a * (129 - a) / 2 + (b - a)) * 64 + n];
        } else {                                     // triple (a=s0, b=s1, c=cb+j)
            int a = s0, b = s1, c = cb + j;
            if (c >= b) {
                int TP = 45760 - (64 - a) * (65 - a) * (66 - a) / 6;
                int RB = b * (129 - b) / 2 - a * (129 - a) / 2;
                val = wo[(2144 + TP + RB + (c - b)) * 64 + n];
            }
        }
    } else if (s0 == 64) {                           // single (c=cb+j)
        val = wo[(cb + j) * 64 + n];
    }                                                // s0==65 pad -> 0
    g_woTi[e] = (_Float16)val;
}

// passthrough pad columns 64,65
__global__ void k_pad(const float* __restrict__ inp, float* __restrict__ out) {
    int i = blockIdx.x * 256 + threadIdx.x;
    if (i >= NB * 2) return;
    int r = i >> 1, c = 64 + (i & 1);
    out[r * ND + c] = inp[r * ND + c];
}

__global__ __launch_bounds__(256) void k_gemm() {
    __shared__ __attribute__((aligned(16))) _Float16 fl[256 * FS];
    __shared__ unsigned ldesc[CH * 4];
    const int mb = blockIdx.x, ks = blockIdx.y, tid = threadIdx.x;
    const int s0c = ks * CH;
    const int s1c = (s0c + CH < NSTEP) ? s0c + CH : NSTEP;

    {   // stage f tile (256 rows) + chunk descriptors
        const uint4* src = (const uint4*)(g_f + (size_t)mb * 256 * FS);
        uint4* dst = (uint4*)fl;
        for (int e = tid; e < 256 * FS * 2 / 16; e += 256) dst[e] = src[e];
        for (int e = tid; e < (s1c - s0c) * 4; e += 256) ldesc[e] = g_grp[s0c * 4 + e];
    }
    __syncthreads();

    const int wave = tid >> 6, lane = tid & 63, rl = lane & 15, g = lane >> 4;
    const _Float16* fr0 = fl + (wave * 64 +  0 + rl) * FS;
    const _Float16* fr1 = fl + (wave * 64 + 16 + rl) * FS;
    const _Float16* fr2 = fl + (wave * 64 + 32 + rl) * FS;
    const _Float16* fr3 = fl + (wave * 64 + 48 + rl) * FS;

    f32x4 acc[4][4];
#pragma unroll
    for (int a = 0; a < 4; ++a)
#pragma unroll
        for (int q = 0; q < 4; ++q) acc[a][q] = f32x4{0.f, 0.f, 0.f, 0.f};

    f16x8 c0{}, c1{}, c2{}, c3{};
    int cbPrev = -1;

    const _Float16* bptr = g_woTi + (size_t)s0c * 2048 + (g * 16 + rl) * 8;
    f16x8 B0 = *(const f16x8*)(bptr +    0);
    f16x8 B1 = *(const f16x8*)(bptr +  512);
    f16x8 B2 = *(const f16x8*)(bptr + 1024);
    f16x8 B3 = *(const f16x8*)(bptr + 1536);
    bptr += 2048;

    for (int s = s0c; s < s1c; ++s) {
        const unsigned d = ldesc[(s - s0c) * 4 + g];
        const int si0 = d & 255, si1 = (d >> 8) & 255;
        const int cb = __builtin_amdgcn_readfirstlane(d >> 16);
        if (cb != cbPrev) {                      // wave-uniform scalar branch
            cbPrev = cb;
            c0 = *(const f16x8*)(fr0 + cb);
            c1 = *(const f16x8*)(fr1 + cb);
            c2 = *(const f16x8*)(fr2 + cb);
            c3 = *(const f16x8*)(fr3 + cb);
        }
        // prefetch next step's B while computing
        f16x8 nB0 = *(const f16x8*)(bptr +    0);
        f16x8 nB1 = *(const f16x8*)(bptr +  512);
        f16x8 nB2 = *(const f16x8*)(bptr + 1024);
        f16x8 nB3 = *(const f16x8*)(bptr + 1536);
        bptr += 2048;

        const _Float16 p0 = fr0[si0] * fr0[si1];
        const _Float16 p1 = fr1[si0] * fr1[si1];
        const _Float16 p2 = fr2[si0] * fr2[si1];
        const _Float16 p3 = fr3[si0] * fr3[si1];
        const f16x8 a0 = c0 * p0, a1 = c1 * p1, a2 = c2 * p2, a3 = c3 * p3;

        acc[0][0] = __builtin_amdgcn_mfma_f32_16x16x32_f16(a0, B0, acc[0][0], 0, 0, 0);
        acc[0][1] = __builtin_amdgcn_mfma_f32_16x16x32_f16(a0, B1, acc[0][1], 0, 0, 0);
        acc[0][2] = __builtin_amdgcn_mfma_f32_16x16x32_f16(a0, B2, acc[0][2], 0, 0, 0);
        acc[0][3] = __builtin_amdgcn_mfma_f32_16x16x32_f16(a0, B3, acc[0][3], 0, 0, 0);
        acc[1][0] = __builtin_amdgcn_mfma_f32_16x16x32_f16(a1, B0, acc[1][0], 0, 0, 0);
        acc[1][1] = __builtin_amdgcn_mfma_f32_16x16x32_f16(a1, B1, acc[1][1], 0, 0, 0);
        acc[1][2] = __builtin_amdgcn_mfma_f32_16x16x32_f16(a1, B2, acc[1][2], 0, 0, 0);
        acc[1][3] = __builtin_amdgcn_mfma_f32_16x16x32_f16(a1, B3, acc[1][3], 0, 0, 0);
        acc[2][0] = __builtin_amdgcn_mfma_f32_16x16x32_f16(a2, B0, acc[2][0], 0, 0, 0);
        acc[2][1] = __builtin_amdgcn_mfma_f32_16x16x32_f16(a2, B1, acc[2][1], 0, 0, 0);
        acc[2][2] = __builtin_amdgcn_mfma_f32_16x16x32_f16(a2, B2, acc[2][2], 0, 0, 0);
        acc[2][3] = __builtin_amdgcn_mfma_f32_16x16x32_f16(a2, B3, acc[2][3], 0, 0, 0);
        acc[3][0] = __builtin_amdgcn_mfma_f32_16x16x32_f16(a3, B0, acc[3][0], 0, 0, 0);
        acc[3][1] = __builtin_amdgcn_mfma_f32_16x16x32_f16(a3, B1, acc[3][1], 0, 0, 0);
        acc[3][2] = __builtin_amdgcn_mfma_f32_16x16x32_f16(a3, B2, acc[3][2], 0, 0, 0);
        acc[3][3] = __builtin_amdgcn_mfma_f32_16x16x32_f16(a3, B3, acc[3][3], 0, 0, 0);

        B0 = nB0; B1 = nB1; B2 = nB2; B3 = nB3;
    }

    // partials: row = mb*256 + wave*64 + a*16 + g*4 + i2, col = q*16 + rl
    const size_t pbase = ((size_t)ks * NB + mb * 256 + wave * 64) * 64;
#pragma unroll
    for (int a = 0; a < 4; ++a)
#pragma unroll
        for (int q = 0; q < 4; ++q)
#pragma unroll
            for (int i2 = 0; i2 < 4; ++i2)
                g_part[pbase + (size_t)(a * 16 + g * 4 + i2) * 64 + q * 16 + rl] = acc[a][q][i2];
}

// out[:, :64] = inputs + sum_ks partials (vectorized f32x4)
__global__ void k_reduce(const float* __restrict__ inp, float* __restrict__ out) {
    int i = blockIdx.x * 256 + threadIdx.x;          // NB*16
    int r = i >> 4, c4 = (i & 15) * 4;
    const float* ip = inp + r * ND + c4;
    f32x4 acc{ip[0], ip[1], ip[2], ip[3]};
#pragma unroll
    for (int ks = 0; ks < KS; ++ks) {
        f32x4 p = *(const f32x4*)(g_part + ((size_t)ks * NB + r) * 64 + c4);
        acc.x += p.x; acc.y += p.y; acc.z += p.z; acc.w += p.w;
    }
    float* op = out + r * ND + c4;
    op[0] = acc.x; op[1] = acc.y; op[2] = acc.z; op[3] = acc.w;
}

extern "C" void kernel_launch(void* const* d_in, const int* in_sizes, int n_in,
                              void* d_out, int out_size, void* d_ws, size_t ws_size,
                              hipStream_t stream) {
    const float* inp = (const float*)d_in[0];
    const float* fw1 = (const float*)d_in[1];
    const float* fw2 = (const float*)d_in[2];
    const float* fb1 = (const float*)d_in[3];
    const float* wo  = (const float*)d_in[4];
    float* out = (float*)d_out;

    k_desc<<<(NOCT + 255) / 256, 256, 0, stream>>>();
    k_f<<<(NB * FS + 255) / 256, 256, 0, stream>>>(inp, fw1, fw2, fb1);
    k_wot<<<NSTEP * 8, 256, 0, stream>>>(wo);        // NSTEP*2048/256
    k_pad<<<(NB * 2 + 255) / 256, 256, 0, stream>>>(inp, out);
    k_gemm<<<dim3(MB, KS), 256, 0, stream>>>();
    k_reduce<<<NB * 16 / 256, 256, 0, stream>>>(inp, out);
}

// Round 5
// 58.947 us; speedup vs baseline: 3.2521x; 1.0937x over previous
//
#include <hip/hip_runtime.h>
#include <hip/hip_bf16.h>

#define NB      4096
#define ND      66
#define NSTEP   1748                 // padded K / 32
#define KS      48                   // split-K chunks
#define CH      37                   // steps per chunk (48*37 >= 1748)
#define MB      16                   // M blocks of 256 rows
#define FS      72                   // f row stride (halfs)

#define WBLK    (NSTEP*8)            // 13984 prep blocks for woTi
#define FBLK    (NB*FS/256)          // 1152 prep blocks for g_f
#define PBLK    32                   // prep blocks for pad cols

typedef __attribute__((ext_vector_type(8))) _Float16 f16x8;
typedef __attribute__((ext_vector_type(4))) _Float16 f16x4;
typedef __attribute__((ext_vector_type(4))) float    f32x4;

// Static device scratch, fully rewritten every launch (deterministic).
__device__ __attribute__((aligned(16))) _Float16 g_f[NB * FS];
__device__ __attribute__((aligned(16))) _Float16 g_woTi[(size_t)(NSTEP + 1) * 2048];
__device__ __attribute__((aligned(16))) _Float16 g_part[(size_t)KS * MB * 4 * 16 * 256];

// bucket boundaries in octets (sizes 48,156,328,564,864,1228,1656,2148) — all %4==0
__constant__ int c_bb[8] = {0, 48, 204, 532, 1096, 1960, 3188, 4844};

// descriptor for octet o: s0 | s1<<8 | cb<<16 ; value[j] = f[s0]*f[s1]*f[cb+j]
// s0==64 or s1==64 -> sentinel f==1 ; s0==65 -> pad (f==0)
__device__ inline unsigned octet_desc(int o) {
    int t = 0;
#pragma unroll
    for (int i = 1; i < 8; ++i) t += (o >= c_bb[i]);
    int li = o - c_bb[t];
    int P = 8 * t + 8, T = P * (P + 1) / 2;
    int s0, s1;
    if (li == 0)       { s0 = 64; s1 = 64; }
    else if (li <= P)  { s0 = li - 1; s1 = 64; }
    else if (li <= P + T) {
        int r = li - P - 1, a = 0;
        while (r >= P - a) { r -= P - a; ++a; }
        s0 = a; s1 = a + r;
    } else             { s0 = 65; s1 = 65; }
    return (unsigned)s0 | ((unsigned)s1 << 8) | ((unsigned)(8 * t) << 16);
}

// Fused prep: [0,WBLK) build woTi ; [WBLK,WBLK+FBLK) Fourier f ; then pad cols
__global__ void k_prep(const float* __restrict__ inp, const float* __restrict__ fw1,
                       const float* __restrict__ fw2, const float* __restrict__ fb1,
                       const float* __restrict__ wo, float* __restrict__ out) {
    const int bid = blockIdx.x, tid = threadIdx.x;
    if (bid < WBLK) {
        // interleaved fp16 B: element e = [s(11b)][q(2)][g(2)][rl(4)][j(3)]
        int e = bid * 256 + tid;
        int s = e >> 11, r = e & 2047;
        int q = r >> 9, gg = (r >> 7) & 3, rl = (r >> 3) & 15, j = r & 7;
        unsigned d = octet_desc(s * 4 + gg);
        int s0 = d & 255, s1 = (d >> 8) & 255, cb = d >> 16;
        int n = q * 16 + rl;
        float val = 0.0f;
        if (s0 < 64) {
            if (s1 == 64) {                          // pair (a=s0, b=cb+j)
                int a = s0, b = cb + j;
                if (b >= a) val = wo[(64 + a * (129 - a) / 2 + (b - a)) * 64 + n];
            } else {                                 // triple (a=s0, b=s1, c=cb+j)
                int a = s0, b = s1, c = cb + j;
                if (c >= b) {
                    int TP = 45760 - (64 - a) * (65 - a) * (66 - a) / 6;
                    int RB = b * (129 - b) / 2 - a * (129 - a) / 2;
                    val = wo[(2144 + TP + RB + (c - b)) * 64 + n];
                }
            }
        } else if (s0 == 64) {                       // single (c=cb+j)
            val = wo[(cb + j) * 64 + n];
        }
        g_woTi[e] = (_Float16)val;
    } else if (bid < WBLK + FBLK) {
        int i = (bid - WBLK) * 256 + tid;            // NB*FS exact
        int r = i / FS, c = i - r * FS;
        float v;
        if (c < 64)       v = cosf(inp[r * ND + c] * fw1[c] + fb1[c]) * fw2[c];
        else if (c == 64) v = 1.0f;
        else              v = 0.0f;
        g_f[i] = (_Float16)v;
    } else {
        int i = (bid - WBLK - FBLK) * 256 + tid;     // NB*2 exact
        int r = i >> 1, c = 64 + (i & 1);
        out[r * ND + c] = inp[r * ND + c];
    }
}

__global__ __launch_bounds__(256, 3) void k_gemm() {
    __shared__ __attribute__((aligned(16))) _Float16 fl[256 * FS];
    __shared__ unsigned ldesc[CH * 4];
    const int mb = blockIdx.x, ks = blockIdx.y, tid = threadIdx.x;
    const int s0c = ks * CH;
    const int s1c = (s0c + CH < NSTEP) ? s0c + CH : NSTEP;
    const int ns = s1c - s0c;

    {   // stage f tile (256 rows) + compute chunk descriptors inline
        const uint4* src = (const uint4*)(g_f + (size_t)mb * 256 * FS);
        uint4* dst = (uint4*)fl;
        for (int e = tid; e < 256 * FS * 2 / 16; e += 256) dst[e] = src[e];
        for (int e = tid; e < ns * 4; e += 256) ldesc[e] = octet_desc(s0c * 4 + e);
    }
    __syncthreads();

    const int wave = tid >> 6, lane = tid & 63, rl = lane & 15, g = lane >> 4;
    const _Float16* fr0 = fl + (wave * 64 +  0 + rl) * FS;
    const _Float16* fr1 = fl + (wave * 64 + 16 + rl) * FS;
    const _Float16* fr2 = fl + (wave * 64 + 32 + rl) * FS;
    const _Float16* fr3 = fl + (wave * 64 + 48 + rl) * FS;

    f32x4 acc[4][4];
#pragma unroll
    for (int a = 0; a < 4; ++a)
#pragma unroll
        for (int q = 0; q < 4; ++q) acc[a][q] = f32x4{0.f, 0.f, 0.f, 0.f};

    f16x8 c0{}, c1{}, c2{}, c3{};
    _Float16 fa0 = 0, fa1 = 0, fa2 = 0, fa3 = 0;
    int cbPrev = -1;
    unsigned dPrev = 0xFFFFFFFFu;

    const _Float16* bptr = g_woTi + (size_t)s0c * 2048 + lane * 8;
    f16x8 B0 = *(const f16x8*)(bptr +    0);
    f16x8 B1 = *(const f16x8*)(bptr +  512);
    f16x8 B2 = *(const f16x8*)(bptr + 1024);
    f16x8 B3 = *(const f16x8*)(bptr + 1536);
    bptr += 2048;

    for (int s = s0c; s < s1c; ++s) {
        const unsigned d = ldesc[(s - s0c) * 4 + g];
        const int si0 = d & 255, si1 = (d >> 8) & 255;
        const int cb = __builtin_amdgcn_readfirstlane(d >> 16);
        if (__any((d & 255) != (dPrev & 255))) {     // wave-uniform: a-run change
            fa0 = fr0[si0]; fa1 = fr1[si0]; fa2 = fr2[si0]; fa3 = fr3[si0];
        }
        dPrev = d;
        if (cb != cbPrev) {                          // wave-uniform: bucket change
            cbPrev = cb;
            c0 = *(const f16x8*)(fr0 + cb);
            c1 = *(const f16x8*)(fr1 + cb);
            c2 = *(const f16x8*)(fr2 + cb);
            c3 = *(const f16x8*)(fr3 + cb);
        }
        // prefetch next step's B while computing
        f16x8 nB0 = *(const f16x8*)(bptr +    0);
        f16x8 nB1 = *(const f16x8*)(bptr +  512);
        f16x8 nB2 = *(const f16x8*)(bptr + 1024);
        f16x8 nB3 = *(const f16x8*)(bptr + 1536);
        bptr += 2048;

        const _Float16 p0 = fa0 * fr0[si1];
        const _Float16 p1 = fa1 * fr1[si1];
        const _Float16 p2 = fa2 * fr2[si1];
        const _Float16 p3 = fa3 * fr3[si1];
        const f16x8 a0 = c0 * p0, a1 = c1 * p1, a2 = c2 * p2, a3 = c3 * p3;

        acc[0][0] = __builtin_amdgcn_mfma_f32_16x16x32_f16(a0, B0, acc[0][0], 0, 0, 0);
        acc[0][1] = __builtin_amdgcn_mfma_f32_16x16x32_f16(a0, B1, acc[0][1], 0, 0, 0);
        acc[0][2] = __builtin_amdgcn_mfma_f32_16x16x32_f16(a0, B2, acc[0][2], 0, 0, 0);
        acc[0][3] = __builtin_amdgcn_mfma_f32_16x16x32_f16(a0, B3, acc[0][3], 0, 0, 0);
        acc[1][0] = __builtin_amdgcn_mfma_f32_16x16x32_f16(a1, B0, acc[1][0], 0, 0, 0);
        acc[1][1] = __builtin_amdgcn_mfma_f32_16x16x32_f16(a1, B1, acc[1][1], 0, 0, 0);
        acc[1][2] = __builtin_amdgcn_mfma_f32_16x16x32_f16(a1, B2, acc[1][2], 0, 0, 0);
        acc[1][3] = __builtin_amdgcn_mfma_f32_16x16x32_f16(a1, B3, acc[1][3], 0, 0, 0);
        acc[2][0] = __builtin_amdgcn_mfma_f32_16x16x32_f16(a2, B0, acc[2][0], 0, 0, 0);
        acc[2][1] = __builtin_amdgcn_mfma_f32_16x16x32_f16(a2, B1, acc[2][1], 0, 0, 0);
        acc[2][2] = __builtin_amdgcn_mfma_f32_16x16x32_f16(a2, B2, acc[2][2], 0, 0, 0);
        acc[2][3] = __builtin_amdgcn_mfma_f32_16x16x32_f16(a2, B3, acc[2][3], 0, 0, 0);
        acc[3][0] = __builtin_amdgcn_mfma_f32_16x16x32_f16(a3, B0, acc[3][0], 0, 0, 0);
        acc[3][1] = __builtin_amdgcn_mfma_f32_16x16x32_f16(a3, B1, acc[3][1], 0, 0, 0);
        acc[3][2] = __builtin_amdgcn_mfma_f32_16x16x32_f16(a3, B2, acc[3][2], 0, 0, 0);
        acc[3][3] = __builtin_amdgcn_mfma_f32_16x16x32_f16(a3, B3, acc[3][3], 0, 0, 0);

        B0 = nB0; B1 = nB1; B2 = nB2; B3 = nB3;
    }

    // fp16 partials, layout [ks][mb][wave][a][q][lane][i2] — 8B vector store/lane
    _Float16* pp = g_part + ((((size_t)ks * MB + mb) * 4 + wave) * 16) * 256;
#pragma unroll
    for (int a = 0; a < 4; ++a)
#pragma unroll
        for (int q = 0; q < 4; ++q) {
            f16x4 v;
            v[0] = (_Float16)acc[a][q][0]; v[1] = (_Float16)acc[a][q][1];
            v[2] = (_Float16)acc[a][q][2]; v[3] = (_Float16)acc[a][q][3];
            *(f16x4*)(pp + (a * 4 + q) * 256 + lane * 4) = v;
        }
}

// out[:, :64] = inputs + sum_ks partials
__global__ void k_reduce(const float* __restrict__ inp, float* __restrict__ out) {
    int t = blockIdx.x * 256 + threadIdx.x;          // 65536 threads
    int c = t & 63, rg = t >> 6;
    int mb = rg >> 6, wave = (rg >> 4) & 3, a = (rg >> 2) & 3, g = rg & 3;
    int q = c >> 4, rl = c & 15, lane = g * 16 + rl;
    int rbase = mb * 256 + wave * 64 + a * 16 + g * 4;
    float acc[4];
#pragma unroll
    for (int i2 = 0; i2 < 4; ++i2) acc[i2] = inp[(rbase + i2) * ND + c];
    const _Float16* pp = g_part + ((((size_t)mb * 4 + wave) * 16) + a * 4 + q) * 256 + lane * 4;
#pragma unroll
    for (int ks = 0; ks < KS; ++ks) {
        const f16x4 p = *(const f16x4*)(pp + (size_t)ks * MB * 4 * 16 * 256);
#pragma unroll
        for (int i2 = 0; i2 < 4; ++i2) acc[i2] += (float)p[i2];
    }
#pragma unroll
    for (int i2 = 0; i2 < 4; ++i2) out[(rbase + i2) * ND + c] = acc[i2];
}

extern "C" void kernel_launch(void* const* d_in, const int* in_sizes, int n_in,
                              void* d_out, int out_size, void* d_ws, size_t ws_size,
                              hipStream_t stream) {
    const float* inp = (const float*)d_in[0];
    const float* fw1 = (const float*)d_in[1];
    const float* fw2 = (const float*)d_in[2];
    const float* fb1 = (const float*)d_in[3];
    const float* wo  = (const float*)d_in[4];
    float* out = (float*)d_out;

    k_prep<<<WBLK + FBLK + PBLK, 256, 0, stream>>>(inp, fw1, fw2, fb1, wo, out);
    k_gemm<<<dim3(MB, KS), 256, 0, stream>>>();
    k_reduce<<<256, 256, 0, stream>>>(inp, out);
}